// Round 6
// baseline (503.168 us; speedup 1.0000x reference)
//
#include <hip/hip_runtime.h>
#include <math.h>

// Problem dims
#define D 256
#define NEF 8192        // feature codebook
#define NEC 1024        // class codebook

// Output layout (flat float32): loss | quantized[257*64*3*256] | f_perp | c_perp | idx[257*64*3]
#define OUT_QBASE   1
#define OUT_FPERP   12632065
#define OUT_CPERP   12632066
#define OUT_IDXBASE 12632067

// Scratch inside the quantized output region (rewritten by vq_gather later;
// fmerge completes before gather launches -> no overlap race). Float offsets:
#define F_SC  0           // feature rescored scores [16384 row][4 part][8]
#define F_IX  524288      // feature candidate codebook idx (int view)
#define C_SC  1048576     // class   rescored scores [64 row][4 part][8]
#define C_IX  1050624
#define EBF_F 1064963     // bf16 feature codebook, row-major (byte addr %16==0)
#define EBF_C 2113539     // bf16 class codebook

// Workspace layout (bytes)
#define WS_CNTF  0        // 8192 int
#define WS_CNTC  32768    // 1024 int
#define WS_LOSS  36864    // float[2]: loss_c, loss_f
#define WS_E2F   49152    // 8192 float
#define WS_E2C   81920    // 1024 float

typedef short bf8 __attribute__((ext_vector_type(8)));     // 8 bf16 (4 VGPRs)
typedef float f32x4 __attribute__((ext_vector_type(4)));   // MFMA C/D frag

// float -> bf16 bits, round-to-nearest-even (coarse pass only)
__device__ __forceinline__ unsigned f2bf(float f) {
    union { float f; unsigned u; } v; v.f = f;
    return (v.u + 0x7FFFu + ((v.u >> 16) & 1u)) >> 16;
}

// Lexicographic (score, idx) insert — EXACT-path only (fmerge). Matches
// jax.lax.top_k stable tie-breaking.
__device__ __forceinline__ void insert3(float s, int idx, float* bs, int* bi) {
    bool lt2 = (s < bs[2]) || (s == bs[2] && idx < bi[2]);
    if (lt2) {
        bool lt1 = (s < bs[1]) || (s == bs[1] && idx < bi[1]);
        if (lt1) {
            bs[2] = bs[1]; bi[2] = bi[1];
            bool lt0 = (s < bs[0]) || (s == bs[0] && idx < bi[0]);
            if (lt0) { bs[1] = bs[0]; bi[1] = bi[0]; bs[0] = s; bi[0] = idx; }
            else     { bs[1] = s;     bi[1] = idx; }
        } else       { bs[2] = s;     bi[2] = idx; }
    }
}

// Coarse top-3 insert, score-only (tie order immaterial: exact rescore decides)
__device__ __forceinline__ void insert3c(float s, int idx, float* bs, int* bi) {
    if (s < bs[2]) {
        bs[2] = s; bi[2] = idx;
        if (bs[2] < bs[1]) {
            float t = bs[1]; bs[1] = bs[2]; bs[2] = t;
            int   u = bi[1]; bi[1] = bi[2]; bi[2] = u;
            if (bs[1] < bs[0]) {
                t = bs[0]; bs[0] = bs[1]; bs[1] = t;
                u = bi[0]; bi[0] = bi[1]; bi[1] = u;
            }
        }
    }
}

// Coarse top-8 insert (score-only)
__device__ __forceinline__ void insert8(float s, int idx, float* hs, int* hi) {
    if (s < hs[7]) {
        hs[7] = s; hi[7] = idx;
#pragma unroll
        for (int q = 7; q > 0; --q) {
            if (hs[q] < hs[q - 1]) {
                float ts = hs[q]; hs[q] = hs[q - 1]; hs[q - 1] = ts;
                int   ti = hi[q]; hi[q] = hi[q - 1]; hi[q - 1] = ti;
            }
        }
    }
}

// ---- fused: codebook norms + fp32->bf16 convert + workspace zeroing
__global__ __launch_bounds__(256)
void vq_prep(const float* __restrict__ femb, const float* __restrict__ cemb,
             unsigned short* __restrict__ ebf_f, unsigned short* __restrict__ ebf_c,
             float* __restrict__ e2f, float* __restrict__ e2c,
             int* __restrict__ counts_f, int* __restrict__ counts_c,
             float* __restrict__ loss)
{
    int zid = blockIdx.x * 256 + threadIdx.x;
    if (zid < 8192)      counts_f[zid] = 0;
    else if (zid < 9216) counts_c[zid - 8192] = 0;
    else if (zid < 9218) loss[zid - 9216] = 0.f;

    int wave = blockIdx.x * 4 + (threadIdx.x >> 6);
    int lane = threadIdx.x & 63;
    const float* src; unsigned short* dst; float* ndst;
    if (wave < NEF) { src = femb + (size_t)wave * D; dst = ebf_f + (size_t)wave * D; ndst = e2f + wave; }
    else { int w2 = wave - NEF; src = cemb + (size_t)w2 * D; dst = ebf_c + (size_t)w2 * D; ndst = e2c + w2; }
    float4 v = *(const float4*)(src + lane * 4);
    uint2 o;
    o.x = f2bf(v.x) | (f2bf(v.y) << 16);
    o.y = f2bf(v.z) | (f2bf(v.w) << 16);
    *(uint2*)(dst + lane * 4) = o;
    float s = v.x * v.x + v.y * v.y + v.z * v.z + v.w * v.w;
#pragma unroll
    for (int off = 32; off > 0; off >>= 1) s += __shfl_down(s, off);
    if (lane == 0) *ndst = s;
}

// ---- coarse bf16-MFMA pass, R6 structure: BARRIER-FREE K-loop.
// Only X lives in LDS (staged once, read-only). E fragments load directly
// global(L2)->VGPR. MFMA operand roles swapped vs R4/R5: A = emb strip,
// B = X rows (both operands use lane->(idx=l&15, k=q4*8) layout; C gets
// col=l15 -> X-row, rows=quad*4+reg -> emb, per m89). Per-lane top-3 state
// is 2 rows only. Waves run fully decoupled; compiler pipelines E loads
// with vmcnt(N) (no forced drain anywhere in the loop).
// Grid swizzle: XCD id = blk&7 (m09 round-robin) pins the emb partition
// pt = (blk&7)>>1, so each XCD's 4MB L2 re-reads only its 1MB quarter.
__global__ __launch_bounds__(256, 4)
void vq_coarse(const float* __restrict__ features,
               const unsigned short* __restrict__ ebf_f,
               const unsigned short* __restrict__ ebf_c,
               const float* __restrict__ femb, const float* __restrict__ cemb,
               const float* __restrict__ e2f, const float* __restrict__ e2c,
               float* __restrict__ out)
{
    __shared__ uint4 sm[2048];   // 32 KB: X only (64 rows x 256 k, bf16 frags)
    const int tid = threadIdx.x, lane = tid & 63, w = tid >> 6;
    const int l15 = lane & 15, q4 = lane >> 4;
    const int wr = w & 1, we = w >> 1;        // row-half, emb-half of the wave grid
    const int blk = blockIdx.x;
    const bool is_class = blk >= 1024;

    const float* xbase; const unsigned short* ebf; const float* e2p;
    const float* cb; const float* e2full;
    int nchunks, eoff, rt = 0, pt = 0;
    if (is_class) {
        int p = blk - 1024;
        xbase = features; ebf = ebf_c; cb = cemb; e2full = e2c;
        e2p = e2c + p * 256; eoff = p * 256; nchunks = 2;
    } else {
        int x = blk & 7;
        pt = x >> 1;                          // emb partition pinned to XCD pair
        rt = ((blk >> 3) << 1) | (x & 1);     // row tile 0..255
        xbase = features + (size_t)(64 + rt * 64) * D;
        ebf = ebf_f; cb = femb; e2full = e2f;
        e2p = e2f + pt * 2048; eoff = pt * 2048; nchunks = 16;
    }
    const unsigned short* ebp = ebf + (size_t)eoff * D;

    // stage X once: fp32 global -> bf16 frags (R4 pattern, verified).
    // Layout: sm[s*256 + row*4 + gp], gp = (k8&3) ^ ((row>>1)&3), k8 = s*4+...
#pragma unroll
    for (int i = 0; i < 8; ++i) {
        int gi = tid + 256 * i;
        int row = gi >> 5, k8 = gi & 31;
        const float* sp = xbase + (size_t)gi * 8;
        float4 a = *(const float4*)sp, b = *(const float4*)(sp + 4);
        uint4 o;
        o.x = f2bf(a.x) | (f2bf(a.y) << 16);
        o.y = f2bf(a.z) | (f2bf(a.w) << 16);
        o.z = f2bf(b.x) | (f2bf(b.y) << 16);
        o.w = f2bf(b.z) | (f2bf(b.w) << 16);
        int s = k8 >> 2, gp = (k8 & 3) ^ ((row >> 1) & 3);
        sm[s * 256 + row * 4 + gp] = o;
    }
    __syncthreads();   // the ONLY barrier before the merge phase

    const int swz = q4 ^ ((l15 >> 1) & 3);
    const int x0s = (wr * 32 + l15) * 4 + swz;        // X frag slot, row-tile 0
    const int x1s = (wr * 32 + 16 + l15) * 4 + swz;   // row-tile 1 (+ s*256)

    float bsc[2][3]; int bix[2][3];   // top-3 for this lane's 2 rows
#pragma unroll
    for (int i = 0; i < 2; ++i)
#pragma unroll
        for (int s3 = 0; s3 < 3; ++s3) { bsc[i][s3] = 1e30f; bix[i][s3] = 0x7FFFFFFF; }

    for (int c = 0; c < nchunks; ++c) {
        // lane's E base: emb = we*64 + et*16 + l15, k = s*32 + q4*8
        const unsigned short* ec = ebp + (size_t)(c * 128 + we * 64 + l15) * D + q4 * 8;
        f32x4 acc[2][4];
#pragma unroll
        for (int i = 0; i < 2; ++i)
#pragma unroll
            for (int et = 0; et < 4; ++et) acc[i][et] = (f32x4){0.f, 0.f, 0.f, 0.f};
        bf8 ea[4], eb[4];
#pragma unroll
        for (int et = 0; et < 4; ++et)
            ea[et] = *(const bf8*)(ec + (size_t)et * 16 * D);
#pragma unroll
        for (int s = 0; s < 8; ++s) {
            if (s < 7) {   // prefetch next slice's E strips (no barrier: stays in flight)
#pragma unroll
                for (int et = 0; et < 4; ++et)
                    eb[et] = *(const bf8*)(ec + (size_t)et * 16 * D + (s + 1) * 32);
            }
            const uint4* xb = sm + s * 256;
            bf8 xf0 = *(const bf8*)(xb + x0s);
            bf8 xf1 = *(const bf8*)(xb + x1s);
#pragma unroll
            for (int et = 0; et < 4; ++et) {
                acc[0][et] = __builtin_amdgcn_mfma_f32_16x16x32_bf16(ea[et], xf0, acc[0][et], 0, 0, 0);
                acc[1][et] = __builtin_amdgcn_mfma_f32_16x16x32_bf16(ea[et], xf1, acc[1][et], 0, 0, 0);
            }
#pragma unroll
            for (int et = 0; et < 4; ++et) ea[et] = eb[et];
        }
        // fold chunk scores: lane's C rows are embs (q4*4+r), cols its 2 X-rows
#pragma unroll
        for (int et = 0; et < 4; ++et) {
#pragma unroll
            for (int r = 0; r < 4; ++r) {
                int el = c * 128 + we * 64 + et * 16 + q4 * 4 + r;
                float e2v = e2p[el];
                insert3c(fmaf(-2.f, acc[0][et][r], e2v), el, bsc[0], bix[0]);
                insert3c(fmaf(-2.f, acc[1][et][r], e2v), el, bsc[1], bix[1]);
            }
        }
    }

    // block merge: per row, 8 partial lists (2 emb-half waves x 4 quads) x top3
    __syncthreads();   // chunk-loop X reads done; alias sm as merge scratch
    float* msc = (float*)sm;          // [64 row][8 part][3]
    int*   mix = (int*)sm + 1536;
    int*   topix = (int*)sm + 3072;   // [64][8]
#pragma unroll
    for (int rt2 = 0; rt2 < 2; ++rt2) {
        int row = wr * 32 + rt2 * 16 + l15;
        int part = we * 4 + q4;
#pragma unroll
        for (int s3 = 0; s3 < 3; ++s3) {
            msc[(row * 8 + part) * 3 + s3] = bsc[rt2][s3];
            mix[(row * 8 + part) * 3 + s3] = bix[rt2][s3];
        }
    }
    __syncthreads();
    if (tid < 64) {
        float hs[8]; int hi[8];
#pragma unroll
        for (int q = 0; q < 8; ++q) { hs[q] = 1e30f; hi[q] = 0x7FFFFFFF; }
        for (int t = 0; t < 24; ++t)
            insert8(msc[tid * 24 + t], mix[tid * 24 + t], hs, hi);
#pragma unroll
        for (int q = 0; q < 8; ++q) topix[tid * 8 + q] = hi[q];
    }
    __syncthreads();

    // exact fp32 rescore (bit-identical chain to R3-R5: single acc, ascending
    // k, score = fmaf(-2, acc, e2)) -> partition candidate lists
    float* base = out + OUT_QBASE;
    int* ibase = (int*)base;
    for (int it = 0; it < 2; ++it) {
        int row = it * 32 + (tid >> 3), cand = tid & 7;
        int el = topix[row * 8 + cand];
        int eg = eoff + el;
        const float* xp = xbase + (size_t)row * D;
        const float* ep = cb + (size_t)eg * D;
        float acc1 = 0.f;
#pragma unroll 4
        for (int qq = 0; qq < 64; ++qq) {
            float4 x = *(const float4*)(xp + qq * 4);
            float4 e = *(const float4*)(ep + qq * 4);
            acc1 = fmaf(x.x, e.x, acc1);
            acc1 = fmaf(x.y, e.y, acc1);
            acc1 = fmaf(x.z, e.z, acc1);
            acc1 = fmaf(x.w, e.w, acc1);
        }
        float sc = fmaf(-2.f, acc1, e2full[eg]);
        if (is_class) {
            int p = blk - 1024;
            base [C_SC + ((size_t)row * 4 + p) * 8 + cand] = sc;
            ibase[C_IX + ((size_t)row * 4 + p) * 8 + cand] = eg;
        } else {
            size_t gr = (size_t)rt * 64 + row;
            base [F_SC + (gr * 4 + pt) * 8 + cand] = sc;
            ibase[F_IX + (gr * 4 + pt) * 8 + cand] = eg;
        }
    }
}

// ---- final merge across the 4 partitions: exact top-3, indices + counts
__global__ __launch_bounds__(256)
void vq_fmerge(float* __restrict__ out, int* __restrict__ counts_f,
               int* __restrict__ counts_c)
{
    const int tid = threadIdx.x, blk = blockIdx.x;
    const float* base = out + OUT_QBASE;
    const int* ibase = (const int*)base;
    if (blk < 64) {
        size_t r = (size_t)blk * 256 + tid;   // feature row
        float fb[3] = {1e30f, 1e30f, 1e30f};
        int   fi[3] = {0x7FFFFFFF, 0x7FFFFFFF, 0x7FFFFFFF};
        for (int t = 0; t < 32; ++t)
            insert3(base[F_SC + r * 32 + t], ibase[F_IX + r * 32 + t], fb, fi);
#pragma unroll
        for (int s = 0; s < 3; ++s) {
            out[OUT_IDXBASE + (64 + r) * 3 + s] = (float)(fi[s] + NEC);
            atomicAdd(&counts_f[fi[s]], 1);
        }
    } else if (tid < 64) {
        size_t r = (size_t)tid;               // class row
        float fb[3] = {1e30f, 1e30f, 1e30f};
        int   fi[3] = {0x7FFFFFFF, 0x7FFFFFFF, 0x7FFFFFFF};
        for (int t = 0; t < 32; ++t)
            insert3(base[C_SC + r * 32 + t], ibase[C_IX + r * 32 + t], fb, fi);
#pragma unroll
        for (int s = 0; s < 3; ++s) {
            out[OUT_IDXBASE + r * 3 + s] = (float)fi[s];
            atomicAdd(&counts_c[fi[s]], 1);
        }
    }
}

// ---- gather emb[idx] -> quantized output + losses. One block per 64 rows.
__global__ __launch_bounds__(256)
void vq_gather(const float* __restrict__ features, const float* __restrict__ femb,
               const float* __restrict__ cemb, float* __restrict__ out,
               float* __restrict__ loss)
{
    __shared__ int sidx[192];
    __shared__ float red[256];
    const int tid = threadIdx.x, b = blockIdx.x;
    if (tid < 192) sidx[tid] = (int)out[OUT_IDXBASE + (size_t)b * 192 + tid];
    __syncthreads();
    const float* xb = features + (size_t)b * 64 * D;
    float lsum = 0.f;
    const int g = tid >> 4, l16 = tid & 15;
    for (int rs = g; rs < 192; rs += 16) {
        int rloc = rs / 3, slot = rs - rloc * 3;
        int idx = sidx[rs];
        const float* ep = (b == 0) ? cemb + (size_t)idx * D
                                   : femb + (size_t)(idx - NEC) * D;
        const float* xp = xb + (size_t)rloc * D;
        size_t ob = OUT_QBASE + (((size_t)b * 64 + rloc) * 3 + slot) * D;
#pragma unroll
        for (int qq = 0; qq < 4; ++qq) {
            int kk = (qq * 16 + l16) * 4;
            float4 e = *(const float4*)(ep + kk);
            float4 x = *(const float4*)(xp + kk);
            float dx = e.x - x.x, dy = e.y - x.y, dz = e.z - x.z, dw = e.w - x.w;
            lsum += dx * dx + dy * dy + dz * dz + dw * dw;
            out[ob + kk + 0] = e.x; out[ob + kk + 1] = e.y;
            out[ob + kk + 2] = e.z; out[ob + kk + 3] = e.w;
        }
    }
    red[tid] = lsum;
    __syncthreads();
    for (int st = 128; st > 0; st >>= 1) {
        if (tid < st) red[tid] += red[tid + st];
        __syncthreads();
    }
    if (tid == 0) atomicAdd(b == 0 ? loss + 0 : loss + 1, red[0]);
}

// ---- scalar epilogue: perplexities + loss
__global__ __launch_bounds__(256)
void vq_finalize(float* __restrict__ out, const int* __restrict__ counts_f,
                 const int* __restrict__ counts_c, const float* __restrict__ loss)
{
    __shared__ double dred[256];
    const int tid = threadIdx.x;
    double acc = 0.0;
    for (int i = tid; i < NEF; i += 256) {
        double p = (double)counts_f[i] / 16384.0;
        acc += p * log(p + 1e-10);
    }
    dred[tid] = acc;
    __syncthreads();
    for (int st = 128; st > 0; st >>= 1) {
        if (tid < st) dred[tid] += dred[tid + st];
        __syncthreads();
    }
    double ent_f = -dred[0];
    __syncthreads();
    acc = 0.0;
    for (int i = tid; i < NEC; i += 256) {
        double p = (double)counts_c[i] / 64.0;
        acc += p * log(p + 1e-10);
    }
    dred[tid] = acc;
    __syncthreads();
    for (int st = 128; st > 0; st >>= 1) {
        if (tid < st) dred[tid] += dred[tid + st];
        __syncthreads();
    }
    double ent_c = -dred[0];
    if (tid == 0) {
        out[OUT_FPERP] = (float)exp(ent_f);
        out[OUT_CPERP] = (float)exp(ent_c);
        out[0] = 1.25f * (loss[0] / 49152.0f + loss[1] / 12582912.0f);
    }
}

extern "C" void kernel_launch(void* const* d_in, const int* in_sizes, int n_in,
                              void* d_out, int out_size, void* d_ws, size_t ws_size,
                              hipStream_t stream)
{
    const float* features = (const float*)d_in[0];  // [257*64, 256]
    const float* cemb     = (const float*)d_in[1];  // [1024, 256]
    const float* femb     = (const float*)d_in[2];  // [8192, 256]
    float* out = (float*)d_out;
    char*  ws  = (char*)d_ws;

    int*   counts_f = (int*)  (ws + WS_CNTF);
    int*   counts_c = (int*)  (ws + WS_CNTC);
    float* loss     = (float*)(ws + WS_LOSS);
    float* e2f      = (float*)(ws + WS_E2F);
    float* e2c      = (float*)(ws + WS_E2C);

    unsigned short* ebf_f = (unsigned short*)(out + OUT_QBASE + EBF_F);
    unsigned short* ebf_c = (unsigned short*)(out + OUT_QBASE + EBF_C);

    vq_prep<<<2304, 256, 0, stream>>>(femb, cemb, ebf_f, ebf_c, e2f, e2c,
                                      counts_f, counts_c, loss);
    vq_coarse<<<1028, 256, 0, stream>>>(features, ebf_f, ebf_c, femb, cemb,
                                        e2f, e2c, out);
    vq_fmerge<<<65, 256, 0, stream>>>(out, counts_f, counts_c);
    vq_gather<<<257, 256, 0, stream>>>(features, femb, cemb, out, loss);
    vq_finalize<<<1, 256, 0, stream>>>(out, counts_f, counts_c, loss);
}